// Round 14
// baseline (234.560 us; speedup 1.0000x reference)
//
#include <hip/hip_runtime.h>
#include <math.h>

#define HID 128
#define INDIM 6

typedef float4 f4;
typedef __attribute__((ext_vector_type(8))) short short8;
typedef __attribute__((ext_vector_type(4))) float f32x4;

static __device__ inline unsigned short f2bf(float f) {
    union { float f; unsigned int u; } v; v.f = f;
    unsigned int r = v.u + 0x7fffu + ((v.u >> 16) & 1u);   // RNE
    return (unsigned short)(r >> 16);
}
static __device__ inline float bf2f_lo(unsigned int u) {
    union { unsigned int u; float f; } v; v.u = u << 16; return v.f;
}
static __device__ inline float bf2f_hi(unsigned int u) {
    union { unsigned int u; float f; } v; v.u = u & 0xffff0000u; return v.f;
}

// ---------------- utility: zero degi[N] + bnbuf[4096] in one launch ----------------
__global__ void k_zero2(int* a, int na, int* b, int nb) {
    int i = blockIdx.x * blockDim.x + threadIdx.x;
    if (i < na) a[i] = 0;
    if (i < nb) b[i] = 0;
}

// ---------------- degree + per-edge rank ----------------
__global__ void k_deg(const int* dst, int* deg, int* rank, int E) {
    int e = blockIdx.x * blockDim.x + threadIdx.x;
    if (e < E) rank[e] = atomicAdd(&deg[dst[e]], 1);
}

// ---------------- hierarchical exclusive scan (deg -> rowptr) ----------------
__global__ void k_scan_partial(const int* __restrict__ deg, int* __restrict__ partial, int N) {
    __shared__ int lds[256];
    int t = threadIdx.x;
    int base = blockIdx.x * 1024 + t * 4;
    int s = 0;
    if (base + 4 <= N) {
        int4 v = *(const int4*)&deg[base];
        s = v.x + v.y + v.z + v.w;
    } else {
        for (int i = 0; i < 4; i++) if (base + i < N) s += deg[base + i];
    }
    lds[t] = s;
    __syncthreads();
    for (int off = 128; off > 0; off >>= 1) {
        if (t < off) lds[t] += lds[t + off];
        __syncthreads();
    }
    if (t == 0) partial[blockIdx.x] = lds[0];
}

__global__ void k_scan_tops(int* partial, int nb) {
    __shared__ int lds[1024];
    int t = threadIdx.x;
    lds[t] = (t < nb) ? partial[t] : 0;
    __syncthreads();
    for (int off = 1; off < 1024; off <<= 1) {
        int v = (t >= off) ? lds[t - off] : 0;
        __syncthreads();
        lds[t] += v;
        __syncthreads();
    }
    if (t < nb) partial[t] = (t == 0) ? 0 : lds[t - 1];
}

__global__ void k_scan_write(const int* __restrict__ deg, const int* __restrict__ partial,
                             int* __restrict__ rowptr, int N, int E) {
    __shared__ int lds[256];
    int t = threadIdx.x;
    int base = blockIdx.x * 1024 + t * 4;
    int v0 = 0, v1 = 0, v2 = 0, v3 = 0;
    if (base + 4 <= N) {
        int4 v = *(const int4*)&deg[base];
        v0 = v.x; v1 = v.y; v2 = v.z; v3 = v.w;
    } else {
        if (base + 0 < N) v0 = deg[base + 0];
        if (base + 1 < N) v1 = deg[base + 1];
        if (base + 2 < N) v2 = deg[base + 2];
        if (base + 3 < N) v3 = deg[base + 3];
    }
    lds[t] = v0 + v1 + v2 + v3;
    __syncthreads();
    for (int off = 1; off < 256; off <<= 1) {
        int v = (t >= off) ? lds[t - off] : 0;
        __syncthreads();
        lds[t] += v;
        __syncthreads();
    }
    int run = partial[blockIdx.x] + ((t == 0) ? 0 : lds[t - 1]);
    if (base + 0 < N) rowptr[base + 0] = run; run += v0;
    if (base + 1 < N) rowptr[base + 1] = run; run += v1;
    if (base + 2 < N) rowptr[base + 2] = run; run += v2;
    if (base + 3 < N) rowptr[base + 3] = run; run += v3;
    if (blockIdx.x == 0 && t == 0) rowptr[N] = E;
}

// ---------------- CSR fill, atomic-free (uses rank from k_deg) ----------------
__global__ void k_fill(const int* ei, const int* rank, const int* rowptr, int* csr, int E) {
    int e = blockIdx.x * blockDim.x + threadIdx.x;
    if (e < E) {
        int d = ei[E + e];
        csr[rowptr[d] + rank[e]] = ei[e];
    }
}

__global__ void k_invdeg(const int* deg, float* invd, int N) {
    int i = blockIdx.x * blockDim.x + threadIdx.x;
    if (i < N) invd[i] = 1.0f / (float)max(deg[i], 1);
}

// ---------------- weight prep: concat [Wl1 | Wr1] -> bf16 [128][256] ----------------
__global__ void k_prepw(const float* __restrict__ wl, const float* __restrict__ wr,
                        unsigned short* __restrict__ wcat) {
    int i = blockIdx.x * 256 + threadIdx.x;       // 32768 total
    int o = i >> 8, k = i & 255;
    float v = (k < 128) ? wl[o * 128 + k] : wr[o * 128 + k - 128];
    wcat[i] = f2bf(v);
}

// ---------------- layer 0a: gather mean6 + in-register h for BN0 stats ----------------
// 32 nodes/block, 8 threads/node (6 active in gather). LDS-staged padded weights.
__global__ __launch_bounds__(256) void k_l0stats(
        const float* __restrict__ x, const int* __restrict__ rowptr,
        const int* __restrict__ csr, const float* __restrict__ invd,
        const float* __restrict__ wl, const float* __restrict__ bl,
        const float* __restrict__ wr, float* __restrict__ mean6,
        float* __restrict__ sum8, float* __restrict__ sq8, int N) {
    __shared__ float wlds[1600];   // [wl | wr], addr = base + o*6+i + (o>>4)*2  (bank-spread)
    __shared__ float blds[136];    // bias, addr = o + (o>>4)
    __shared__ float mx[32][8];
    __shared__ float xr[32][8];
    __shared__ float ps[4][128];
    __shared__ float pq[4][128];
    int t = threadIdx.x;
    for (int idx = t; idx < 1536; idx += 256) {
        int half = idx >= 768 ? 1 : 0;
        int lin = idx - half * 768;
        int o = lin / 6, i = lin - o * 6;
        float v = half ? wr[lin] : wl[lin];
        wlds[half * 800 + o * 6 + i + (o >> 4) * 2] = v;
    }
    if (t < 128) blds[t + (t >> 4)] = bl[t];
    int nl = t >> 3, f = t & 7;
    int n = blockIdx.x * 32 + nl;
    bool valid = n < N;
    if (f < 6) {
        float mean = 0.f, xv = 0.f;
        if (valid) {
            int s = rowptr[n], e = rowptr[n + 1];
            float acc = 0.f;
            int i = s;
            for (; i + 4 <= e; i += 4) {           // 4-deep MLP unroll
                int i0 = csr[i], i1 = csr[i + 1], i2 = csr[i + 2], i3 = csr[i + 3];
                float a0 = x[i0 * 6 + f], a1 = x[i1 * 6 + f];
                float a2 = x[i2 * 6 + f], a3 = x[i3 * 6 + f];
                acc += (a0 + a1) + (a2 + a3);
            }
            for (; i < e; i++) acc += x[csr[i] * 6 + f];
            mean = acc * invd[n];
            xv = x[n * 6 + f];
            mean6[n * 6 + f] = mean;               // 2.4 MB total (replaces 51 MB h write)
        }
        mx[nl][f] = mean;
        xr[nl][f] = xv;
    }
    __syncthreads();
    float m0 = mx[nl][0], m1 = mx[nl][1], m2 = mx[nl][2];
    float m3 = mx[nl][3], m4 = mx[nl][4], m5 = mx[nl][5];
    float r0 = xr[nl][0], r1 = xr[nl][1], r2 = xr[nl][2];
    float r3 = xr[nl][3], r4 = xr[nl][4], r5 = xr[nl][5];
    const float* wA = wlds;
    const float* wB = wlds + 800;
    float sk[16], qk[16];
#pragma unroll
    for (int k4 = 0; k4 < 4; k4++) {
#pragma unroll
        for (int j = 0; j < 4; j++) {
            int k = k4 * 4 + j;
            int o = f * 16 + k;
            int wb = 98 * f + 6 * k;            // o*6 + (o>>4)*2
            float h = blds[o + f];              // o + (o>>4), o>>4 == f
            h += m0 * wA[wb] + m1 * wA[wb + 1] + m2 * wA[wb + 2]
               + m3 * wA[wb + 3] + m4 * wA[wb + 4] + m5 * wA[wb + 5];
            h += r0 * wB[wb] + r1 * wB[wb + 1] + r2 * wB[wb + 2]
               + r3 * wB[wb + 3] + r4 * wB[wb + 4] + r5 * wB[wb + 5];
            float hs = valid ? h : 0.f;
            sk[k] = hs;
            qk[k] = hs * hs;
        }
    }
    // stats: reduce over the wave's 8 nodes (lane bits 3..5), then LDS, then 8-copy atomics
    int wv = t >> 6, lane = t & 63;
#pragma unroll
    for (int k = 0; k < 16; k++) {
        float s = sk[k], q = qk[k];
        s += __shfl_xor(s, 8, 64);  q += __shfl_xor(q, 8, 64);
        s += __shfl_xor(s, 16, 64); q += __shfl_xor(q, 16, 64);
        s += __shfl_xor(s, 32, 64); q += __shfl_xor(q, 32, 64);
        if (lane < 8) { ps[wv][lane * 16 + k] = s; pq[wv][lane * 16 + k] = q; }
    }
    __syncthreads();
    if (t < 128) {
        float S = ps[0][t] + ps[1][t] + ps[2][t] + ps[3][t];
        float Q = pq[0][t] + pq[1][t] + pq[2][t] + pq[3][t];
        int slot = (blockIdx.x & 7) * 128 + t;
        atomicAdd(&sum8[slot], S);
        atomicAdd(&sq8[slot], Q);
    }
}

// ---------------- layer 0b: recompute h (identical code) + BN0+ReLU -> bf16 ----------
__global__ __launch_bounds__(256) void k_l0apply(
        const float* __restrict__ x, const float* __restrict__ mean6,
        const float* __restrict__ wl, const float* __restrict__ bl,
        const float* __restrict__ wr, const float* __restrict__ scale,
        const float* __restrict__ shift, unsigned short* __restrict__ out, int N) {
    __shared__ float wlds[1600];
    __shared__ float blds[136];
    __shared__ float sclds[136];
    __shared__ float shlds[136];
    __shared__ float mx[32][8];
    __shared__ float xr[32][8];
    int t = threadIdx.x;
    for (int idx = t; idx < 1536; idx += 256) {
        int half = idx >= 768 ? 1 : 0;
        int lin = idx - half * 768;
        int o = lin / 6, i = lin - o * 6;
        float v = half ? wr[lin] : wl[lin];
        wlds[half * 800 + o * 6 + i + (o >> 4) * 2] = v;
    }
    if (t < 128) {
        blds[t + (t >> 4)]  = bl[t];
        sclds[t + (t >> 4)] = scale[t];
        shlds[t + (t >> 4)] = shift[t];
    }
    int nl = t >> 3, f = t & 7;
    int n = blockIdx.x * 32 + nl;
    bool valid = n < N;
    if (f < 6) {
        mx[nl][f] = valid ? mean6[n * 6 + f] : 0.f;
        xr[nl][f] = valid ? x[n * 6 + f] : 0.f;
    }
    __syncthreads();
    if (!valid) return;
    float m0 = mx[nl][0], m1 = mx[nl][1], m2 = mx[nl][2];
    float m3 = mx[nl][3], m4 = mx[nl][4], m5 = mx[nl][5];
    float r0 = xr[nl][0], r1 = xr[nl][1], r2 = xr[nl][2];
    float r3 = xr[nl][3], r4 = xr[nl][4], r5 = xr[nl][5];
    const float* wA = wlds;
    const float* wB = wlds + 800;
    unsigned short pk[16];
#pragma unroll
    for (int k4 = 0; k4 < 4; k4++) {
#pragma unroll
        for (int j = 0; j < 4; j++) {
            int k = k4 * 4 + j;
            int o = f * 16 + k;
            int wb = 98 * f + 6 * k;
            float h = blds[o + f];              // identical expression tree to k_l0stats
            h += m0 * wA[wb] + m1 * wA[wb + 1] + m2 * wA[wb + 2]
               + m3 * wA[wb + 3] + m4 * wA[wb + 4] + m5 * wA[wb + 5];
            h += r0 * wB[wb] + r1 * wB[wb + 1] + r2 * wB[wb + 2]
               + r3 * wB[wb + 3] + r4 * wB[wb + 4] + r5 * wB[wb + 5];
            pk[k] = f2bf(fmaxf(0.f, fmaf(h, sclds[o + f], shlds[o + f])));
        }
    }
    unsigned short* dst = out + (size_t)n * HID + f * 16;
    *(uint4*)(dst)     = *(const uint4*)&pk[0];
    *(uint4*)(dst + 8) = *(const uint4*)&pk[8];
}

// ---------------- BN finalize from 8-copy accumulators ----------------
__global__ void k_bnfin8(const float* sum8, const float* sq8, const float* g, const float* b,
                         float* scale, float* shift, float invN) {
    int t = threadIdx.x;
    float s = 0.f, q = 0.f;
    for (int c = 0; c < 8; c++) { s += sum8[c * 128 + t]; q += sq8[c * 128 + t]; }
    float mu  = s * invN;
    float var = q * invN - mu * mu;
    float sc  = g[t] * rsqrtf(var + 1e-5f);
    scale[t] = sc;
    shift[t] = b[t] - mu * sc;
}

// ---------------- bf16 mean aggregation: half-wave per node, uint2 lanes, 4-deep MLP ----
__global__ void k_agg_bf(const unsigned short* __restrict__ hb, const int* __restrict__ rowptr,
                         const int* __restrict__ csr, const float* __restrict__ invd,
                         unsigned short* __restrict__ out, int N) {
    int t = threadIdx.x;
    int w = t >> 6, lid = t & 63;
    int half = lid >> 5, l32 = lid & 31;
    int n = blockIdx.x * 8 + w * 2 + half;
    if (n >= N) return;
    int s = rowptr[n], e = rowptr[n + 1];
    const uint2* hb64 = (const uint2*)hb;          // row stride = 32 uint2 (256 B)
    float ax0 = 0.f, ay0 = 0.f, ax1 = 0.f, ay1 = 0.f;
    int i = s;
    for (; i + 4 <= e; i += 4) {                   // 4 rows x 2 nodes/wave in flight
        int i0 = csr[i], i1 = csr[i + 1], i2 = csr[i + 2], i3 = csr[i + 3];
        uint2 u0 = hb64[(size_t)i0 * 32 + l32];
        uint2 u1 = hb64[(size_t)i1 * 32 + l32];
        uint2 u2 = hb64[(size_t)i2 * 32 + l32];
        uint2 u3 = hb64[(size_t)i3 * 32 + l32];
        ax0 += (bf2f_lo(u0.x) + bf2f_lo(u1.x)) + (bf2f_lo(u2.x) + bf2f_lo(u3.x));
        ay0 += (bf2f_hi(u0.x) + bf2f_hi(u1.x)) + (bf2f_hi(u2.x) + bf2f_hi(u3.x));
        ax1 += (bf2f_lo(u0.y) + bf2f_lo(u1.y)) + (bf2f_lo(u2.y) + bf2f_lo(u3.y));
        ay1 += (bf2f_hi(u0.y) + bf2f_hi(u1.y)) + (bf2f_hi(u2.y) + bf2f_hi(u3.y));
    }
    for (; i < e; i++) {
        uint2 u = hb64[(size_t)csr[i] * 32 + l32];
        ax0 += bf2f_lo(u.x); ay0 += bf2f_hi(u.x);
        ax1 += bf2f_lo(u.y); ay1 += bf2f_hi(u.y);
    }
    float id = invd[n];
    uint2 r;
    r.x = (unsigned int)f2bf(ax0 * id) | ((unsigned int)f2bf(ay0 * id) << 16);
    r.y = (unsigned int)f2bf(ax1 * id) | ((unsigned int)f2bf(ay1 * id) << 16);
    ((uint2*)out)[(size_t)n * 32 + l32] = r;
}

// ---------------- MFMA double GEMM + fused BN1 stats ----------------
// block: 128 rows x 128 cols, 4 waves (2x2 of 64x64), K = 256 (chunks of 32)
__global__ __launch_bounds__(256) void k_gemm(
        const unsigned short* __restrict__ Bm, const unsigned short* __restrict__ Ar,
        const unsigned short* __restrict__ wcat, const float* __restrict__ bias,
        float* __restrict__ sum8, float* __restrict__ sq8,
        float* __restrict__ C, int N) {
    __shared__ __align__(16) unsigned short As[128][40];   // 32 k + 8 pad
    __shared__ __align__(16) unsigned short Ws[128][40];
    __shared__ float lds_s[2][128];
    __shared__ float lds_q[2][128];
    int t = threadIdx.x;
    int wave = t >> 6, lane = t & 63;
    int wr = wave >> 1, wc = wave & 1;
    int row0 = blockIdx.x * 128;
    int r = t >> 1, half = t & 1;          // staging: row r, 16-col half

    f32x4 acc[4][4];
#pragma unroll
    for (int m = 0; m < 4; m++)
#pragma unroll
        for (int n = 0; n < 4; n++) acc[m][n] = (f32x4)(0.f);

    for (int chunk = 0; chunk < 8; chunk++) {
        int kb = chunk * 32;
        // ---- stage A (bf16 copy) ----
        int srow = row0 + r;
        int c0 = (chunk & 3) * 32 + half * 16;
        const unsigned short* src = (chunk < 4) ? Bm : Ar;
        if (srow < N) {
            const unsigned short* p = src + (size_t)srow * HID + c0;
            *(uint4*)&As[r][half * 16]     = *(const uint4*)(p);
            *(uint4*)&As[r][half * 16 + 8] = *(const uint4*)(p + 8);
        } else {
            uint4 z = make_uint4(0, 0, 0, 0);
            *(uint4*)&As[r][half * 16]     = z;
            *(uint4*)&As[r][half * 16 + 8] = z;
        }
        // ---- stage W (bf16, L2-resident) ----
        const unsigned short* wp = wcat + r * 256 + kb + half * 16;
        *(uint4*)&Ws[r][half * 16]     = *(const uint4*)(wp + 0);
        *(uint4*)&Ws[r][half * 16 + 8] = *(const uint4*)(wp + 8);
        __syncthreads();

        // ---- MFMA ----
        int lrow = lane & 15, koff = (lane >> 4) * 8;
        short8 af[4], bfr[4];
#pragma unroll
        for (int m = 0; m < 4; m++)
            af[m] = *(const short8*)&As[wr * 64 + m * 16 + lrow][koff];
#pragma unroll
        for (int n = 0; n < 4; n++)
            bfr[n] = *(const short8*)&Ws[wc * 64 + n * 16 + lrow][koff];
#pragma unroll
        for (int m = 0; m < 4; m++)
#pragma unroll
            for (int n = 0; n < 4; n++)
                acc[m][n] = __builtin_amdgcn_mfma_f32_16x16x32_bf16(af[m], bfr[n], acc[m][n], 0, 0, 0);
        __syncthreads();
    }

    // ---- epilogue: store + per-col stats. D: col = lane&15, row = (lane>>4)*4 + reg ----
    int cl = lane & 15, rq = (lane >> 4) * 4;
    float cs[4], cq[4];
#pragma unroll
    for (int n = 0; n < 4; n++) {
        int col = wc * 64 + n * 16 + cl;
        float bn = bias[col];
        float s = 0.f, q = 0.f;
#pragma unroll
        for (int m = 0; m < 4; m++) {
#pragma unroll
            for (int reg = 0; reg < 4; reg++) {
                int row = row0 + wr * 64 + m * 16 + rq + reg;
                float v = acc[m][n][reg] + bn;
                if (row < N) {
                    C[(size_t)row * HID + col] = v;
                    s += v;
                    q += v * v;
                }
            }
        }
        cs[n] = s; cq[n] = q;
    }
#pragma unroll
    for (int n = 0; n < 4; n++) {
        float s = cs[n], q = cq[n];
        s += __shfl_xor(s, 16, 64); q += __shfl_xor(q, 16, 64);
        s += __shfl_xor(s, 32, 64); q += __shfl_xor(q, 32, 64);
        if (lane < 16) {
            int col = wc * 64 + n * 16 + cl;   // cl == lane
            lds_s[wr][col] = s;
            lds_q[wr][col] = q;
        }
    }
    __syncthreads();
    if (t < 128) {
        float S = lds_s[0][t] + lds_s[1][t];
        float Q = lds_q[0][t] + lds_q[1][t];
        int slot = (blockIdx.x & 7) * 128 + t;
        atomicAdd(&sum8[slot], S);
        atomicAdd(&sq8[slot], Q);
    }
}

// ---------------- layer 2 dots: s = relu(bn1(h))·wl2, r = relu(bn1(h))·wr2 ----------------
__global__ void k_dots(const float* __restrict__ h, const float* __restrict__ scale,
                       const float* __restrict__ shift, const float* __restrict__ wl2,
                       const float* __restrict__ wr2, float* __restrict__ s_arr,
                       float* __restrict__ r_arr, int N) {
    int w = threadIdx.x >> 6, lid = threadIdx.x & 63;
    int n = blockIdx.x * 4 + w;
    if (n >= N) return;
    float2 v  = *(const float2*)&h[(size_t)n * HID + lid * 2];
    float2 sc = *(const float2*)&scale[lid * 2];
    float2 sh = *(const float2*)&shift[lid * 2];
    float y0 = fmaxf(0.f, fmaf(v.x, sc.x, sh.x));
    float y1 = fmaxf(0.f, fmaf(v.y, sc.y, sh.y));
    float2 wl = *(const float2*)&wl2[lid * 2];
    float2 wrv = *(const float2*)&wr2[lid * 2];
    float ps = y0 * wl.x + y1 * wl.y;
    float pr = y0 * wrv.x + y1 * wrv.y;
#pragma unroll
    for (int off = 32; off > 0; off >>= 1) {
        ps += __shfl_down(ps, off, 64);
        pr += __shfl_down(pr, off, 64);
    }
    if (lid == 0) { s_arr[n] = ps; r_arr[n] = pr; }
}

// ---------------- final: scalar mean over edges + sigmoid (4-deep MLP) ----------------
__global__ void k_final2(const float* __restrict__ s_arr, const float* __restrict__ r_arr,
                         const int* __restrict__ rowptr, const int* __restrict__ csr,
                         const float* __restrict__ invd, const float* __restrict__ bl2,
                         float* __restrict__ out, int N) {
    int n = blockIdx.x * blockDim.x + threadIdx.x;
    if (n >= N) return;
    int s = rowptr[n], e = rowptr[n + 1];
    float a = 0.f;
    int i = s;
    for (; i + 4 <= e; i += 4) {
        float a0 = s_arr[csr[i]],     a1 = s_arr[csr[i + 1]];
        float a2 = s_arr[csr[i + 2]], a3 = s_arr[csr[i + 3]];
        a += (a0 + a1) + (a2 + a3);
    }
    for (; i < e; i++) a += s_arr[csr[i]];
    float p = a * invd[n] + r_arr[n] + bl2[0];
    out[n] = 1.f / (1.f + expf(-p));
}

// ---------------- host ----------------
extern "C" void kernel_launch(void* const* d_in, const int* in_sizes, int n_in,
                              void* d_out, int out_size, void* d_ws, size_t ws_size,
                              hipStream_t stream) {
    const float* x   = (const float*)d_in[0];
    const int*   ei  = (const int*)d_in[1];
    const float* wl0 = (const float*)d_in[2];
    const float* bl0 = (const float*)d_in[3];
    const float* wr0 = (const float*)d_in[4];
    const float* g0  = (const float*)d_in[5];
    const float* be0 = (const float*)d_in[6];
    const float* wl1 = (const float*)d_in[7];
    const float* bl1 = (const float*)d_in[8];
    const float* wr1 = (const float*)d_in[9];
    const float* g1  = (const float*)d_in[10];
    const float* be1 = (const float*)d_in[11];
    const float* wl2 = (const float*)d_in[12];
    const float* bl2 = (const float*)d_in[13];
    const float* wr2 = (const float*)d_in[14];
    float* outp = (float*)d_out;

    int N = in_sizes[0] / INDIM;     // 100000
    int E = in_sizes[1] / 2;         // 600000

    char* ws = (char*)d_ws;
    size_t off = 0;
    auto alloc = [&](size_t bytes) { size_t o = off; off = (off + bytes + 255) & ~(size_t)255; return o; };
    int*   degi   = (int*)(ws + alloc((size_t)N * 4));
    int*   rank   = (int*)(ws + alloc((size_t)E * 4));
    int*   rowptr = (int*)(ws + alloc((size_t)(N + 1) * 4));
    int*   csr    = (int*)(ws + alloc((size_t)E * 4));
    float* invd   = (float*)(ws + alloc((size_t)N * 4));
    int*   partial= (int*)(ws + alloc(1024 * 4));
    float* bnbuf  = (float*)(ws + alloc(5120 * 4));
    unsigned short* wcat = (unsigned short*)(ws + alloc(128 * 256 * 2));
    float* sarr   = (float*)(ws + alloc((size_t)N * 4));
    float* rarr   = (float*)(ws + alloc((size_t)N * 4));
    float* mean6  = (float*)(ws + alloc((size_t)N * 6 * 4));
    // bnbuf layout: sum0_8[1024] sq0_8[1024] sum1_8[1024] sq1_8[1024] sc0 sh0 sc1 sh1 [128 each]
    float* sum0_8 = bnbuf;
    float* sq0_8  = bnbuf + 1024;
    float* sum1_8 = bnbuf + 2048;
    float* sq1_8  = bnbuf + 3072;
    float* sc0 = bnbuf + 4096, *sh0 = bnbuf + 4224;
    float* sc1 = bnbuf + 4352, *sh1 = bnbuf + 4480;
    float* bufB = (float*)(ws + alloc((size_t)N * HID * 4));            // gemm out (raw pre-BN1)
    unsigned short* bufC = (unsigned short*)(ws + alloc((size_t)N * HID * 2)); // bf16 relu(bn0)
    unsigned short* bufD = (unsigned short*)(ws + alloc((size_t)N * HID * 2)); // bf16 agg mean

    float invN = 1.0f / (float)N;
    int gE = (E + 255) / 256;
    int gN = (N + 255) / 256;
    int gW = (N + 3) / 4;            // wave-per-node kernels
    int gA = (N + 7) / 8;            // agg blocks (8 nodes each, half-wave per node)
    int gL = (N + 31) / 32;          // layer0 blocks (32 nodes each)
    int gS = (N + 127) / 128;        // gemm blocks
    int nbScan = (N + 1023) / 1024;

    // zero degree + BN accumulators in one launch
    k_zero2<<<gN, 256, 0, stream>>>(degi, N, (int*)bnbuf, 4096);

    // weight prep (independent)
    k_prepw<<<128, 256, 0, stream>>>(wl1, wr1, wcat);

    // CSR build (rank-based, atomic-free fill)
    k_deg<<<gE, 256, 0, stream>>>(ei + E, degi, rank, E);
    k_scan_partial<<<nbScan, 256, 0, stream>>>(degi, partial, N);
    k_scan_tops<<<1, 1024, 0, stream>>>(partial, nbScan);
    k_scan_write<<<nbScan, 256, 0, stream>>>(degi, partial, rowptr, N, E);
    k_fill<<<gE, 256, 0, stream>>>(ei, rank, rowptr, csr, E);
    k_invdeg<<<gN, 256, 0, stream>>>(degi, invd, N);

    // layer 0a: gather mean6 + fused BN0 stats (h in-register, discarded)
    k_l0stats<<<gL, 256, 0, stream>>>(x, rowptr, csr, invd, wl0, bl0, wr0, mean6,
                                      sum0_8, sq0_8, N);
    k_bnfin8<<<1, 128, 0, stream>>>(sum0_8, sq0_8, g0, be0, sc0, sh0, invN);

    // layer 0b: recompute h (identical fp32 ops) + BN0+ReLU -> bf16 bufC
    k_l0apply<<<gL, 256, 0, stream>>>(x, mean6, wl0, bl0, wr0, sc0, sh0, bufC, N);

    // layer 1: agg(bufC) -> bufD (bf16) ; MFMA gemm(bufD, bufC) -> bufB with fused BN1 stats
    k_agg_bf<<<gA, 256, 0, stream>>>(bufC, rowptr, csr, invd, bufD, N);
    k_gemm<<<gS, 256, 0, stream>>>(bufD, bufC, wcat, bl1, sum1_8, sq1_8, bufB, N);
    k_bnfin8<<<1, 128, 0, stream>>>(sum1_8, sq1_8, g1, be1, sc1, sh1, invN);

    // layer 2: per-node dots then scalar aggregation + sigmoid
    k_dots<<<gW, 256, 0, stream>>>(bufB, sc1, sh1, wl2, wr2, sarr, rarr, N);
    k_final2<<<gN, 256, 0, stream>>>(sarr, rarr, rowptr, csr, invd, bl2, outp, N);
}

// Round 15
// 210.113 us; speedup vs baseline: 1.1164x; 1.1164x over previous
//
#include <hip/hip_runtime.h>
#include <math.h>

#define HID 128
#define INDIM 6

typedef float4 f4;
typedef __attribute__((ext_vector_type(8))) short short8;
typedef __attribute__((ext_vector_type(4))) float f32x4;

static __device__ inline unsigned short f2bf(float f) {
    union { float f; unsigned int u; } v; v.f = f;
    unsigned int r = v.u + 0x7fffu + ((v.u >> 16) & 1u);   // RNE
    return (unsigned short)(r >> 16);
}
static __device__ inline float bf2f_lo(unsigned int u) {
    union { unsigned int u; float f; } v; v.u = u << 16; return v.f;
}
static __device__ inline float bf2f_hi(unsigned int u) {
    union { unsigned int u; float f; } v; v.u = u & 0xffff0000u; return v.f;
}

// ---------------- utility: zero degi[N] + bnbuf[4096] in one launch ----------------
__global__ void k_zero2(int* a, int na, int* b, int nb) {
    int i = blockIdx.x * blockDim.x + threadIdx.x;
    if (i < na) a[i] = 0;
    if (i < nb) b[i] = 0;
}

// ---------------- degree + per-edge rank ----------------
__global__ void k_deg(const int* dst, int* deg, int* rank, int E) {
    int e = blockIdx.x * blockDim.x + threadIdx.x;
    if (e < E) rank[e] = atomicAdd(&deg[dst[e]], 1);
}

// ---------------- hierarchical exclusive scan (deg -> rowptr) ----------------
__global__ void k_scan_partial(const int* __restrict__ deg, int* __restrict__ partial, int N) {
    __shared__ int lds[256];
    int t = threadIdx.x;
    int base = blockIdx.x * 1024 + t * 4;
    int s = 0;
    if (base + 4 <= N) {
        int4 v = *(const int4*)&deg[base];
        s = v.x + v.y + v.z + v.w;
    } else {
        for (int i = 0; i < 4; i++) if (base + i < N) s += deg[base + i];
    }
    lds[t] = s;
    __syncthreads();
    for (int off = 128; off > 0; off >>= 1) {
        if (t < off) lds[t] += lds[t + off];
        __syncthreads();
    }
    if (t == 0) partial[blockIdx.x] = lds[0];
}

__global__ void k_scan_tops(int* partial, int nb) {
    __shared__ int lds[1024];
    int t = threadIdx.x;
    lds[t] = (t < nb) ? partial[t] : 0;
    __syncthreads();
    for (int off = 1; off < 1024; off <<= 1) {
        int v = (t >= off) ? lds[t - off] : 0;
        __syncthreads();
        lds[t] += v;
        __syncthreads();
    }
    if (t < nb) partial[t] = (t == 0) ? 0 : lds[t - 1];
}

__global__ void k_scan_write(const int* __restrict__ deg, const int* __restrict__ partial,
                             int* __restrict__ rowptr, int N, int E) {
    __shared__ int lds[256];
    int t = threadIdx.x;
    int base = blockIdx.x * 1024 + t * 4;
    int v0 = 0, v1 = 0, v2 = 0, v3 = 0;
    if (base + 4 <= N) {
        int4 v = *(const int4*)&deg[base];
        v0 = v.x; v1 = v.y; v2 = v.z; v3 = v.w;
    } else {
        if (base + 0 < N) v0 = deg[base + 0];
        if (base + 1 < N) v1 = deg[base + 1];
        if (base + 2 < N) v2 = deg[base + 2];
        if (base + 3 < N) v3 = deg[base + 3];
    }
    lds[t] = v0 + v1 + v2 + v3;
    __syncthreads();
    for (int off = 1; off < 256; off <<= 1) {
        int v = (t >= off) ? lds[t - off] : 0;
        __syncthreads();
        lds[t] += v;
        __syncthreads();
    }
    int run = partial[blockIdx.x] + ((t == 0) ? 0 : lds[t - 1]);
    if (base + 0 < N) rowptr[base + 0] = run; run += v0;
    if (base + 1 < N) rowptr[base + 1] = run; run += v1;
    if (base + 2 < N) rowptr[base + 2] = run; run += v2;
    if (base + 3 < N) rowptr[base + 3] = run; run += v3;
    if (blockIdx.x == 0 && t == 0) rowptr[N] = E;
}

// ---------------- CSR fill, atomic-free (uses rank from k_deg) ----------------
__global__ void k_fill(const int* ei, const int* rank, const int* rowptr, int* csr, int E) {
    int e = blockIdx.x * blockDim.x + threadIdx.x;
    if (e < E) {
        int d = ei[E + e];
        csr[rowptr[d] + rank[e]] = ei[e];
    }
}

__global__ void k_invdeg(const int* deg, float* invd, int N) {
    int i = blockIdx.x * blockDim.x + threadIdx.x;
    if (i < N) invd[i] = 1.0f / (float)max(deg[i], 1);
}

// ---------------- weight prep: concat [Wl1 | Wr1] -> bf16 [128][256] ----------------
__global__ void k_prepw(const float* __restrict__ wl, const float* __restrict__ wr,
                        unsigned short* __restrict__ wcat) {
    int i = blockIdx.x * 256 + threadIdx.x;       // 32768 total
    int o = i >> 8, k = i & 255;
    float v = (k < 128) ? wl[o * 128 + k] : wr[o * 128 + k - 128];
    wcat[i] = f2bf(v);
}

// ---------------- layer 0a: gather mean6 + in-register h for BN0 stats ----------------
// 32 nodes/block, 8 threads/node (6 active in gather). Inline per-k reduction keeps
// VGPR low (R14 regression: sk[16]/qk[16] arrays blew VGPR 36->112, occupancy 51->18%).
__global__ __launch_bounds__(256) void k_l0stats(
        const float* __restrict__ x, const int* __restrict__ rowptr,
        const int* __restrict__ csr, const float* __restrict__ invd,
        const float* __restrict__ wl, const float* __restrict__ bl,
        const float* __restrict__ wr, float* __restrict__ mean6,
        float* __restrict__ sum8, float* __restrict__ sq8, int N) {
    __shared__ float wlds[1600];   // [wl | wr], addr = base + o*6+i + (o>>4)*2  (bank-spread)
    __shared__ float blds[136];    // bias, addr = o + (o>>4)
    __shared__ float mx[32][8];
    __shared__ float xr[32][8];
    __shared__ float ps[4][128];
    __shared__ float pq[4][128];
    int t = threadIdx.x;
    for (int idx = t; idx < 1536; idx += 256) {
        int half = idx >= 768 ? 1 : 0;
        int lin = idx - half * 768;
        int o = lin / 6, i = lin - o * 6;
        float v = half ? wr[lin] : wl[lin];
        wlds[half * 800 + o * 6 + i + (o >> 4) * 2] = v;
    }
    if (t < 128) blds[t + (t >> 4)] = bl[t];
    int nl = t >> 3, f = t & 7;
    int n = blockIdx.x * 32 + nl;
    bool valid = n < N;
    if (f < 6) {
        float mean = 0.f, xv = 0.f;
        if (valid) {
            int s = rowptr[n], e = rowptr[n + 1];
            float acc = 0.f;
            int i = s;
            for (; i + 4 <= e; i += 4) {           // 4-deep MLP unroll
                int i0 = csr[i], i1 = csr[i + 1], i2 = csr[i + 2], i3 = csr[i + 3];
                float a0 = x[i0 * 6 + f], a1 = x[i1 * 6 + f];
                float a2 = x[i2 * 6 + f], a3 = x[i3 * 6 + f];
                acc += (a0 + a1) + (a2 + a3);
            }
            for (; i < e; i++) acc += x[csr[i] * 6 + f];
            mean = acc * invd[n];
            xv = x[n * 6 + f];
            mean6[n * 6 + f] = mean;               // 2.4 MB total (replaces 51 MB h write)
        }
        mx[nl][f] = mean;
        xr[nl][f] = xv;
    }
    __syncthreads();
    float m0 = mx[nl][0], m1 = mx[nl][1], m2 = mx[nl][2];
    float m3 = mx[nl][3], m4 = mx[nl][4], m5 = mx[nl][5];
    float r0 = xr[nl][0], r1 = xr[nl][1], r2 = xr[nl][2];
    float r3 = xr[nl][3], r4 = xr[nl][4], r5 = xr[nl][5];
    const float* wA = wlds;
    const float* wB = wlds + 800;
    int wv = t >> 6, lane = t & 63;
#pragma unroll
    for (int k = 0; k < 16; k++) {                 // inline reduce: no sk/qk arrays
        int o = f * 16 + k;
        int wb = 98 * f + 6 * k;                   // o*6 + (o>>4)*2
        float h = blds[o + f];                     // o + (o>>4), o>>4 == f
        h += m0 * wA[wb] + m1 * wA[wb + 1] + m2 * wA[wb + 2]
           + m3 * wA[wb + 3] + m4 * wA[wb + 4] + m5 * wA[wb + 5];
        h += r0 * wB[wb] + r1 * wB[wb + 1] + r2 * wB[wb + 2]
           + r3 * wB[wb + 3] + r4 * wB[wb + 4] + r5 * wB[wb + 5];
        float s = valid ? h : 0.f;
        float q = s * s;
        s += __shfl_xor(s, 8, 64);  q += __shfl_xor(q, 8, 64);
        s += __shfl_xor(s, 16, 64); q += __shfl_xor(q, 16, 64);
        s += __shfl_xor(s, 32, 64); q += __shfl_xor(q, 32, 64);
        if (lane < 8) { ps[wv][lane * 16 + k] = s; pq[wv][lane * 16 + k] = q; }
    }
    __syncthreads();
    if (t < 128) {
        float S = ps[0][t] + ps[1][t] + ps[2][t] + ps[3][t];
        float Q = pq[0][t] + pq[1][t] + pq[2][t] + pq[3][t];
        int slot = (blockIdx.x & 7) * 128 + t;
        atomicAdd(&sum8[slot], S);
        atomicAdd(&sq8[slot], Q);
    }
}

// ---------------- layer 0b: recompute h (identical code) + BN0+ReLU -> bf16 ----------
__global__ __launch_bounds__(256) void k_l0apply(
        const float* __restrict__ x, const float* __restrict__ mean6,
        const float* __restrict__ wl, const float* __restrict__ bl,
        const float* __restrict__ wr, const float* __restrict__ scale,
        const float* __restrict__ shift, unsigned short* __restrict__ out, int N) {
    __shared__ float wlds[1600];
    __shared__ float blds[136];
    __shared__ float sclds[136];
    __shared__ float shlds[136];
    __shared__ float mx[32][8];
    __shared__ float xr[32][8];
    int t = threadIdx.x;
    for (int idx = t; idx < 1536; idx += 256) {
        int half = idx >= 768 ? 1 : 0;
        int lin = idx - half * 768;
        int o = lin / 6, i = lin - o * 6;
        float v = half ? wr[lin] : wl[lin];
        wlds[half * 800 + o * 6 + i + (o >> 4) * 2] = v;
    }
    if (t < 128) {
        blds[t + (t >> 4)]  = bl[t];
        sclds[t + (t >> 4)] = scale[t];
        shlds[t + (t >> 4)] = shift[t];
    }
    int nl = t >> 3, f = t & 7;
    int n = blockIdx.x * 32 + nl;
    bool valid = n < N;
    if (f < 6) {
        mx[nl][f] = valid ? mean6[n * 6 + f] : 0.f;
        xr[nl][f] = valid ? x[n * 6 + f] : 0.f;
    }
    __syncthreads();
    if (!valid) return;
    float m0 = mx[nl][0], m1 = mx[nl][1], m2 = mx[nl][2];
    float m3 = mx[nl][3], m4 = mx[nl][4], m5 = mx[nl][5];
    float r0 = xr[nl][0], r1 = xr[nl][1], r2 = xr[nl][2];
    float r3 = xr[nl][3], r4 = xr[nl][4], r5 = xr[nl][5];
    const float* wA = wlds;
    const float* wB = wlds + 800;
    unsigned short pk[16];
#pragma unroll
    for (int k4 = 0; k4 < 4; k4++) {
#pragma unroll
        for (int j = 0; j < 4; j++) {
            int k = k4 * 4 + j;
            int o = f * 16 + k;
            int wb = 98 * f + 6 * k;
            float h = blds[o + f];              // identical expression tree to k_l0stats
            h += m0 * wA[wb] + m1 * wA[wb + 1] + m2 * wA[wb + 2]
               + m3 * wA[wb + 3] + m4 * wA[wb + 4] + m5 * wA[wb + 5];
            h += r0 * wB[wb] + r1 * wB[wb + 1] + r2 * wB[wb + 2]
               + r3 * wB[wb + 3] + r4 * wB[wb + 4] + r5 * wB[wb + 5];
            pk[k] = f2bf(fmaxf(0.f, fmaf(h, sclds[o + f], shlds[o + f])));
        }
    }
    unsigned short* dst = out + (size_t)n * HID + f * 16;
    *(uint4*)(dst)     = *(const uint4*)&pk[0];
    *(uint4*)(dst + 8) = *(const uint4*)&pk[8];
}

// ---------------- BN finalize from 8-copy accumulators ----------------
__global__ void k_bnfin8(const float* sum8, const float* sq8, const float* g, const float* b,
                         float* scale, float* shift, float invN) {
    int t = threadIdx.x;
    float s = 0.f, q = 0.f;
    for (int c = 0; c < 8; c++) { s += sum8[c * 128 + t]; q += sq8[c * 128 + t]; }
    float mu  = s * invN;
    float var = q * invN - mu * mu;
    float sc  = g[t] * rsqrtf(var + 1e-5f);
    scale[t] = sc;
    shift[t] = b[t] - mu * sc;
}

// ---------------- bf16 mean aggregation: half-wave per node, uint2 lanes, 4-deep MLP ----
__global__ void k_agg_bf(const unsigned short* __restrict__ hb, const int* __restrict__ rowptr,
                         const int* __restrict__ csr, const float* __restrict__ invd,
                         unsigned short* __restrict__ out, int N) {
    int t = threadIdx.x;
    int w = t >> 6, lid = t & 63;
    int half = lid >> 5, l32 = lid & 31;
    int n = blockIdx.x * 8 + w * 2 + half;
    if (n >= N) return;
    int s = rowptr[n], e = rowptr[n + 1];
    const uint2* hb64 = (const uint2*)hb;          // row stride = 32 uint2 (256 B)
    float ax0 = 0.f, ay0 = 0.f, ax1 = 0.f, ay1 = 0.f;
    int i = s;
    for (; i + 4 <= e; i += 4) {                   // 4 rows x 2 nodes/wave in flight
        int i0 = csr[i], i1 = csr[i + 1], i2 = csr[i + 2], i3 = csr[i + 3];
        uint2 u0 = hb64[(size_t)i0 * 32 + l32];
        uint2 u1 = hb64[(size_t)i1 * 32 + l32];
        uint2 u2 = hb64[(size_t)i2 * 32 + l32];
        uint2 u3 = hb64[(size_t)i3 * 32 + l32];
        ax0 += (bf2f_lo(u0.x) + bf2f_lo(u1.x)) + (bf2f_lo(u2.x) + bf2f_lo(u3.x));
        ay0 += (bf2f_hi(u0.x) + bf2f_hi(u1.x)) + (bf2f_hi(u2.x) + bf2f_hi(u3.x));
        ax1 += (bf2f_lo(u0.y) + bf2f_lo(u1.y)) + (bf2f_lo(u2.y) + bf2f_lo(u3.y));
        ay1 += (bf2f_hi(u0.y) + bf2f_hi(u1.y)) + (bf2f_hi(u2.y) + bf2f_hi(u3.y));
    }
    for (; i < e; i++) {
        uint2 u = hb64[(size_t)csr[i] * 32 + l32];
        ax0 += bf2f_lo(u.x); ay0 += bf2f_hi(u.x);
        ax1 += bf2f_lo(u.y); ay1 += bf2f_hi(u.y);
    }
    float id = invd[n];
    uint2 r;
    r.x = (unsigned int)f2bf(ax0 * id) | ((unsigned int)f2bf(ay0 * id) << 16);
    r.y = (unsigned int)f2bf(ax1 * id) | ((unsigned int)f2bf(ay1 * id) << 16);
    ((uint2*)out)[(size_t)n * 32 + l32] = r;
}

// ---------------- MFMA double GEMM + fused BN1 stats ----------------
// block: 128 rows x 128 cols, 4 waves (2x2 of 64x64), K = 256 (chunks of 32)
__global__ __launch_bounds__(256) void k_gemm(
        const unsigned short* __restrict__ Bm, const unsigned short* __restrict__ Ar,
        const unsigned short* __restrict__ wcat, const float* __restrict__ bias,
        float* __restrict__ sum8, float* __restrict__ sq8,
        float* __restrict__ C, int N) {
    __shared__ __align__(16) unsigned short As[128][40];   // 32 k + 8 pad
    __shared__ __align__(16) unsigned short Ws[128][40];
    __shared__ float lds_s[2][128];
    __shared__ float lds_q[2][128];
    int t = threadIdx.x;
    int wave = t >> 6, lane = t & 63;
    int wr = wave >> 1, wc = wave & 1;
    int row0 = blockIdx.x * 128;
    int r = t >> 1, half = t & 1;          // staging: row r, 16-col half

    f32x4 acc[4][4];
#pragma unroll
    for (int m = 0; m < 4; m++)
#pragma unroll
        for (int n = 0; n < 4; n++) acc[m][n] = (f32x4)(0.f);

    for (int chunk = 0; chunk < 8; chunk++) {
        int kb = chunk * 32;
        // ---- stage A (bf16 copy) ----
        int srow = row0 + r;
        int c0 = (chunk & 3) * 32 + half * 16;
        const unsigned short* src = (chunk < 4) ? Bm : Ar;
        if (srow < N) {
            const unsigned short* p = src + (size_t)srow * HID + c0;
            *(uint4*)&As[r][half * 16]     = *(const uint4*)(p);
            *(uint4*)&As[r][half * 16 + 8] = *(const uint4*)(p + 8);
        } else {
            uint4 z = make_uint4(0, 0, 0, 0);
            *(uint4*)&As[r][half * 16]     = z;
            *(uint4*)&As[r][half * 16 + 8] = z;
        }
        // ---- stage W (bf16, L2-resident) ----
        const unsigned short* wp = wcat + r * 256 + kb + half * 16;
        *(uint4*)&Ws[r][half * 16]     = *(const uint4*)(wp + 0);
        *(uint4*)&Ws[r][half * 16 + 8] = *(const uint4*)(wp + 8);
        __syncthreads();

        // ---- MFMA ----
        int lrow = lane & 15, koff = (lane >> 4) * 8;
        short8 af[4], bfr[4];
#pragma unroll
        for (int m = 0; m < 4; m++)
            af[m] = *(const short8*)&As[wr * 64 + m * 16 + lrow][koff];
#pragma unroll
        for (int n = 0; n < 4; n++)
            bfr[n] = *(const short8*)&Ws[wc * 64 + n * 16 + lrow][koff];
#pragma unroll
        for (int m = 0; m < 4; m++)
#pragma unroll
            for (int n = 0; n < 4; n++)
                acc[m][n] = __builtin_amdgcn_mfma_f32_16x16x32_bf16(af[m], bfr[n], acc[m][n], 0, 0, 0);
        __syncthreads();
    }

    // ---- epilogue: store + per-col stats. D: col = lane&15, row = (lane>>4)*4 + reg ----
    int cl = lane & 15, rq = (lane >> 4) * 4;
    float cs[4], cq[4];
#pragma unroll
    for (int n = 0; n < 4; n++) {
        int col = wc * 64 + n * 16 + cl;
        float bn = bias[col];
        float s = 0.f, q = 0.f;
#pragma unroll
        for (int m = 0; m < 4; m++) {
#pragma unroll
            for (int reg = 0; reg < 4; reg++) {
                int row = row0 + wr * 64 + m * 16 + rq + reg;
                float v = acc[m][n][reg] + bn;
                if (row < N) {
                    C[(size_t)row * HID + col] = v;
                    s += v;
                    q += v * v;
                }
            }
        }
        cs[n] = s; cq[n] = q;
    }
#pragma unroll
    for (int n = 0; n < 4; n++) {
        float s = cs[n], q = cq[n];
        s += __shfl_xor(s, 16, 64); q += __shfl_xor(q, 16, 64);
        s += __shfl_xor(s, 32, 64); q += __shfl_xor(q, 32, 64);
        if (lane < 16) {
            int col = wc * 64 + n * 16 + cl;   // cl == lane
            lds_s[wr][col] = s;
            lds_q[wr][col] = q;
        }
    }
    __syncthreads();
    if (t < 128) {
        float S = lds_s[0][t] + lds_s[1][t];
        float Q = lds_q[0][t] + lds_q[1][t];
        int slot = (blockIdx.x & 7) * 128 + t;
        atomicAdd(&sum8[slot], S);
        atomicAdd(&sq8[slot], Q);
    }
}

// ---------------- layer 2 dots: s = relu(bn1(h))·wl2, r = relu(bn1(h))·wr2 ----------------
__global__ void k_dots(const float* __restrict__ h, const float* __restrict__ scale,
                       const float* __restrict__ shift, const float* __restrict__ wl2,
                       const float* __restrict__ wr2, float* __restrict__ s_arr,
                       float* __restrict__ r_arr, int N) {
    int w = threadIdx.x >> 6, lid = threadIdx.x & 63;
    int n = blockIdx.x * 4 + w;
    if (n >= N) return;
    float2 v  = *(const float2*)&h[(size_t)n * HID + lid * 2];
    float2 sc = *(const float2*)&scale[lid * 2];
    float2 sh = *(const float2*)&shift[lid * 2];
    float y0 = fmaxf(0.f, fmaf(v.x, sc.x, sh.x));
    float y1 = fmaxf(0.f, fmaf(v.y, sc.y, sh.y));
    float2 wl = *(const float2*)&wl2[lid * 2];
    float2 wrv = *(const float2*)&wr2[lid * 2];
    float ps = y0 * wl.x + y1 * wl.y;
    float pr = y0 * wrv.x + y1 * wrv.y;
#pragma unroll
    for (int off = 32; off > 0; off >>= 1) {
        ps += __shfl_down(ps, off, 64);
        pr += __shfl_down(pr, off, 64);
    }
    if (lid == 0) { s_arr[n] = ps; r_arr[n] = pr; }
}

// ---------------- final: scalar mean over edges + sigmoid (4-deep MLP) ----------------
__global__ void k_final2(const float* __restrict__ s_arr, const float* __restrict__ r_arr,
                         const int* __restrict__ rowptr, const int* __restrict__ csr,
                         const float* __restrict__ invd, const float* __restrict__ bl2,
                         float* __restrict__ out, int N) {
    int n = blockIdx.x * blockDim.x + threadIdx.x;
    if (n >= N) return;
    int s = rowptr[n], e = rowptr[n + 1];
    float a = 0.f;
    int i = s;
    for (; i + 4 <= e; i += 4) {
        float a0 = s_arr[csr[i]],     a1 = s_arr[csr[i + 1]];
        float a2 = s_arr[csr[i + 2]], a3 = s_arr[csr[i + 3]];
        a += (a0 + a1) + (a2 + a3);
    }
    for (; i < e; i++) a += s_arr[csr[i]];
    float p = a * invd[n] + r_arr[n] + bl2[0];
    out[n] = 1.f / (1.f + expf(-p));
}

// ---------------- host ----------------
extern "C" void kernel_launch(void* const* d_in, const int* in_sizes, int n_in,
                              void* d_out, int out_size, void* d_ws, size_t ws_size,
                              hipStream_t stream) {
    const float* x   = (const float*)d_in[0];
    const int*   ei  = (const int*)d_in[1];
    const float* wl0 = (const float*)d_in[2];
    const float* bl0 = (const float*)d_in[3];
    const float* wr0 = (const float*)d_in[4];
    const float* g0  = (const float*)d_in[5];
    const float* be0 = (const float*)d_in[6];
    const float* wl1 = (const float*)d_in[7];
    const float* bl1 = (const float*)d_in[8];
    const float* wr1 = (const float*)d_in[9];
    const float* g1  = (const float*)d_in[10];
    const float* be1 = (const float*)d_in[11];
    const float* wl2 = (const float*)d_in[12];
    const float* bl2 = (const float*)d_in[13];
    const float* wr2 = (const float*)d_in[14];
    float* outp = (float*)d_out;

    int N = in_sizes[0] / INDIM;     // 100000
    int E = in_sizes[1] / 2;         // 600000

    char* ws = (char*)d_ws;
    size_t off = 0;
    auto alloc = [&](size_t bytes) { size_t o = off; off = (off + bytes + 255) & ~(size_t)255; return o; };
    int*   degi   = (int*)(ws + alloc((size_t)N * 4));
    int*   rank   = (int*)(ws + alloc((size_t)E * 4));
    int*   rowptr = (int*)(ws + alloc((size_t)(N + 1) * 4));
    int*   csr    = (int*)(ws + alloc((size_t)E * 4));
    float* invd   = (float*)(ws + alloc((size_t)N * 4));
    int*   partial= (int*)(ws + alloc(1024 * 4));
    float* bnbuf  = (float*)(ws + alloc(5120 * 4));
    unsigned short* wcat = (unsigned short*)(ws + alloc(128 * 256 * 2));
    float* sarr   = (float*)(ws + alloc((size_t)N * 4));
    float* rarr   = (float*)(ws + alloc((size_t)N * 4));
    float* mean6  = (float*)(ws + alloc((size_t)N * 6 * 4));
    // bnbuf layout: sum0_8[1024] sq0_8[1024] sum1_8[1024] sq1_8[1024] sc0 sh0 sc1 sh1 [128 each]
    float* sum0_8 = bnbuf;
    float* sq0_8  = bnbuf + 1024;
    float* sum1_8 = bnbuf + 2048;
    float* sq1_8  = bnbuf + 3072;
    float* sc0 = bnbuf + 4096, *sh0 = bnbuf + 4224;
    float* sc1 = bnbuf + 4352, *sh1 = bnbuf + 4480;
    float* bufB = (float*)(ws + alloc((size_t)N * HID * 4));            // gemm out (raw pre-BN1)
    unsigned short* bufC = (unsigned short*)(ws + alloc((size_t)N * HID * 2)); // bf16 relu(bn0)
    unsigned short* bufD = (unsigned short*)(ws + alloc((size_t)N * HID * 2)); // bf16 agg mean

    float invN = 1.0f / (float)N;
    int gE = (E + 255) / 256;
    int gN = (N + 255) / 256;
    int gW = (N + 3) / 4;            // wave-per-node kernels
    int gA = (N + 7) / 8;            // agg blocks (8 nodes each, half-wave per node)
    int gL = (N + 31) / 32;          // layer0 blocks (32 nodes each)
    int gS = (N + 127) / 128;        // gemm blocks
    int nbScan = (N + 1023) / 1024;

    // zero degree + BN accumulators in one launch
    k_zero2<<<gN, 256, 0, stream>>>(degi, N, (int*)bnbuf, 4096);

    // weight prep (independent)
    k_prepw<<<128, 256, 0, stream>>>(wl1, wr1, wcat);

    // CSR build (rank-based, atomic-free fill)
    k_deg<<<gE, 256, 0, stream>>>(ei + E, degi, rank, E);
    k_scan_partial<<<nbScan, 256, 0, stream>>>(degi, partial, N);
    k_scan_tops<<<1, 1024, 0, stream>>>(partial, nbScan);
    k_scan_write<<<nbScan, 256, 0, stream>>>(degi, partial, rowptr, N, E);
    k_fill<<<gE, 256, 0, stream>>>(ei, rank, rowptr, csr, E);
    k_invdeg<<<gN, 256, 0, stream>>>(degi, invd, N);

    // layer 0a: gather mean6 + fused BN0 stats (h in-register, discarded)
    k_l0stats<<<gL, 256, 0, stream>>>(x, rowptr, csr, invd, wl0, bl0, wr0, mean6,
                                      sum0_8, sq0_8, N);
    k_bnfin8<<<1, 128, 0, stream>>>(sum0_8, sq0_8, g0, be0, sc0, sh0, invN);

    // layer 0b: recompute h (identical fp32 ops) + BN0+ReLU -> bf16 bufC
    k_l0apply<<<gL, 256, 0, stream>>>(x, mean6, wl0, bl0, wr0, sc0, sh0, bufC, N);

    // layer 1: agg(bufC) -> bufD (bf16) ; MFMA gemm(bufD, bufC) -> bufB with fused BN1 stats
    k_agg_bf<<<gA, 256, 0, stream>>>(bufC, rowptr, csr, invd, bufD, N);
    k_gemm<<<gS, 256, 0, stream>>>(bufD, bufC, wcat, bl1, sum1_8, sq1_8, bufB, N);
    k_bnfin8<<<1, 128, 0, stream>>>(sum1_8, sq1_8, g1, be1, sc1, sh1, invN);

    // layer 2: per-node dots then scalar aggregation + sigmoid
    k_dots<<<gW, 256, 0, stream>>>(bufB, sc1, sh1, wl2, wr2, sarr, rarr, N);
    k_final2<<<gN, 256, 0, stream>>>(sarr, rarr, rowptr, csr, invd, bl2, outp, N);
}